// Round 9
// baseline (313.267 us; speedup 1.0000x reference)
//
#include <hip/hip_runtime.h>
#include <math.h>

#define NN 50000
#define NE 800000
#define D_IN 64
#define D_HID 256
#define BN_EPS 1e-5f
#define ZSTR 264   // LDS tile row stride in shorts (+8 pad: 16B-aligned rows, spread banks)

typedef __attribute__((ext_vector_type(8))) short short8;
typedef __attribute__((ext_vector_type(4))) float f32x4;

static __device__ __forceinline__ unsigned short f2bf(float f) {
    unsigned int u = __builtin_bit_cast(unsigned int, f);
    u += 0x7FFFu + ((u >> 16) & 1u);   // round-to-nearest-even
    return (unsigned short)(u >> 16);
}
static __device__ __forceinline__ float bf2f(unsigned short s) {
    unsigned int u = ((unsigned int)s) << 16;
    return __builtin_bit_cast(float, u);
}
// fast sigmoid: rcp(1+e^-x). Saturates cleanly at +/-inf, no NaN.
static __device__ __forceinline__ float fast_sigmoid(float x) {
    return __builtin_amdgcn_rcpf(1.0f + __expf(-x));
}
// fast tanh: 1 - 2*rcp(e^{2x}+1). Saturates cleanly, no NaN.
static __device__ __forceinline__ float fast_tanh(float x) {
    return 1.0f - 2.0f * __builtin_amdgcn_rcpf(__expf(2.0f * x) + 1.0f);
}

// ---------------- setup: zero counters/BN accums + pack all weights (one launch) ----------
// Wp[((ct*KC + kc)*64 + lane)*8 + j] = W[(kc*32 + (lane>>4)*8 + j)*256 + ct*16 + (lane&15)]
__global__ void k_setup(const float* __restrict__ W_gcn, const float* __restrict__ W_lin,
                        const float* __restrict__ W_gate,
                        unsigned short* __restrict__ Wp_gcn, unsigned short* __restrict__ Wp_lin,
                        unsigned short* __restrict__ Wp_gate,
                        int* __restrict__ cnt, float* __restrict__ colsum,
                        float* __restrict__ colsumsq, int n) {
    int idx = blockIdx.x * blockDim.x + threadIdx.x;
    if (idx < n) cnt[idx] = 0;
    if (idx < D_HID) { colsum[idx] = 0.f; colsumsq[idx] = 0.f; }
    if (idx >= 98304) return;
    const float* W;
    unsigned short* Wp;
    int KC, o;
    if (idx < 16384)      { W = W_gcn;  Wp = Wp_gcn;  KC = 2; o = idx; }
    else if (idx < 32768) { W = W_lin;  Wp = Wp_lin;  KC = 2; o = idx - 16384; }
    else                  { W = W_gate; Wp = Wp_gate; KC = 8; o = idx - 32768; }
    int j = o & 7;
    int lane = (o >> 3) & 63;
    int rest = o >> 9;
    int kc = rest % KC;
    int ct = rest / KC;
    int col = ct * 16 + (lane & 15);
    int k = kc * 32 + (lane >> 4) * 8 + j;
    Wp[o] = f2bf(W[k * D_HID + col]);
}

// ---------------- count in-edges per dst: 4 edges/thread via int4 ----------------
__global__ void k_count(const int* __restrict__ eidx, int* __restrict__ cnt, int E) {
    int e4 = blockIdx.x * blockDim.x + threadIdx.x;
    if (e4 * 4 >= E) return;
    int4 d = *(const int4*)(eidx + E + e4 * 4);
    atomicAdd(&cnt[d.x], 1);
    atomicAdd(&cnt[d.y], 1);
    atomicAdd(&cnt[d.z], 1);
    atomicAdd(&cnt[d.w], 1);
}

// ---------------- 2-level exclusive scan over cnt[n] ----------------
__global__ void k_scan1(const int* __restrict__ cnt, int* __restrict__ part,
                        int* __restrict__ bsum, int n) {
    __shared__ int s[256];
    int t = threadIdx.x;
    int i = blockIdx.x * 256 + t;
    int v = (i < n) ? cnt[i] : 0;
    s[t] = v;
    __syncthreads();
    for (int d = 1; d < 256; d <<= 1) {
        int t2 = (t >= d) ? s[t - d] : 0;
        __syncthreads();
        s[t] += t2;
        __syncthreads();
    }
    if (i < n) part[i] = s[t] - v;
    if (t == 255) bsum[blockIdx.x] = s[255];
}

__global__ void k_scan2(int* __restrict__ bsum, int nb) {
    __shared__ int s[256];
    int t = threadIdx.x;
    int v = (t < nb) ? bsum[t] : 0;
    s[t] = v;
    __syncthreads();
    for (int d = 1; d < 256; d <<= 1) {
        int t2 = (t >= d) ? s[t - d] : 0;
        __syncthreads();
        s[t] += t2;
        __syncthreads();
    }
    if (t < nb) bsum[t] = s[t] - v;
}

// A-frag-linear address for element (row i, feature k):
// ((i>>4)*2 + (k>>5))*512 + (((k>>3)&3)*16 + (i&15))*8 + (k&7)
static __device__ __forceinline__ long a_addr(int i, int k) {
    return ((long)((i >> 4) * 2 + (k >> 5)) << 9) + ((((k >> 3) & 3) * 16 + (i & 15)) << 3) + (k & 7);
}

// ---------------- scan fixup + prep fused: offs/cursor + dinv + bf16 features ------------
// grid covers n*8+8 threads; thread (i, sub) handles features sub*8..sub*8+7 of node i.
// last 8 threads zero-fill the sentinel row xscaled[n] (gather tail clamp target).
__global__ void k_scan3p(const int* __restrict__ part, const int* __restrict__ bsum,
                         int* __restrict__ offs, int* __restrict__ cursor,
                         const float* __restrict__ xs, const int* __restrict__ cnt,
                         float* __restrict__ dinv, unsigned short* __restrict__ xscaled,
                         unsigned short* __restrict__ xs_p, int n) {
    int idx = blockIdx.x * 256 + threadIdx.x;
    if (idx < n) {
        int o = part[idx] + bsum[idx >> 8];
        offs[idx] = o;
        cursor[idx] = o;
    }
    if (idx >= n * 8) {
        if (idx < n * 8 + 8) {  // zero sentinel row n
            short8 zv = (short8){0, 0, 0, 0, 0, 0, 0, 0};
            *(short8*)(xscaled + (long)n * D_IN + (idx - n * 8) * 8) = zv;
        }
        return;
    }
    int i = idx >> 3;
    int sub = idx & 7;
    float dv = rsqrtf(1.0f + (float)cnt[i]);
    if (sub == 0) dinv[i] = dv;
    const float* p = xs + (long)i * D_IN + sub * 8;
    float4 f0 = *(const float4*)p;
    float4 f1 = *(const float4*)(p + 4);
    float vals[8] = {f0.x, f0.y, f0.z, f0.w, f1.x, f1.y, f1.z, f1.w};
    short8 xsc, xsb;
#pragma unroll
    for (int j = 0; j < 8; j++) {
        xsc[j] = (short)f2bf(vals[j] * dv);
        xsb[j] = (short)f2bf(vals[j]);
    }
    *(short8*)(xscaled + (long)i * D_IN + sub * 8) = xsc;
    *(short8*)(xs_p + a_addr(i, sub * 8)) = xsb;
}

// ---------------- scatter edges into CSR-by-dst order: 4 edges/thread ----------------
__global__ void k_scatter(const int* __restrict__ eidx, int* __restrict__ cursor,
                          int* __restrict__ csr_src, int E) {
    int e4 = blockIdx.x * blockDim.x + threadIdx.x;
    if (e4 * 4 >= E) return;
    int4 s = *(const int4*)(eidx + e4 * 4);
    int4 d = *(const int4*)(eidx + E + e4 * 4);
    csr_src[atomicAdd(&cursor[d.x], 1)] = s.x;
    csr_src[atomicAdd(&cursor[d.y], 1)] = s.y;
    csr_src[atomicAdd(&cursor[d.z], 1)] = s.z;
    csr_src[atomicAdd(&cursor[d.w], 1)] = s.w;
}

// ---------------- gather aggregation: wave per node, 8 rows x 16B/lane per round ---------
// lane = (grp = lane>>3: row slot, sub = lane&7: feature octet). Wave-uniform t-loop
// bound; tail lanes clamp to zero sentinel row n (no divergent branch around loads).
__global__ __launch_bounds__(256) void k_gather(const int* __restrict__ csr_src,
                                                const int* __restrict__ offs,
                                                const int* __restrict__ cnt,
                                                const unsigned short* __restrict__ xscaled,
                                                const float* __restrict__ dinv,
                                                unsigned short* __restrict__ agg_p, int n) {
    int wv = threadIdx.x >> 6;
    int lane = threadIdx.x & 63;
    int sub = lane & 7;
    int grp = lane >> 3;
    int i = blockIdx.x * 4 + wv;
    if (i >= n) return;
    int start = offs[i];
    int c = cnt[i];
    float acc[8];
#pragma unroll
    for (int j = 0; j < 8; j++) acc[j] = 0.f;
    for (int base = 0; base < c; base += 64) {
        int m = c - base;
        m = m < 64 ? m : 64;
        int idxv = (lane < m) ? csr_src[start + base + lane] : 0;
        int tmax = (m + 7) >> 3;          // wave-uniform trip count
        for (int t = 0; t < tmax; t++) {
            int e = t * 8 + grp;
            int rowv = __shfl(idxv, e);
            int row = (e < m) ? rowv : n;  // clamp tail to zero sentinel row
            short8 v = *(const short8*)(xscaled + (long)row * D_IN + sub * 8);
#pragma unroll
            for (int j = 0; j < 8; j++) acc[j] += bf2f((unsigned short)v[j]);
        }
    }
    // reduce across the 8 row slots (lane bits 3..5)
#pragma unroll
    for (int d = 8; d <= 32; d <<= 1)
#pragma unroll
        for (int j = 0; j < 8; j++) acc[j] += __shfl_xor(acc[j], d);
    if (grp == 0) {
        float dv = dinv[i];
        short8 sv = *(const short8*)(xscaled + (long)i * D_IN + sub * 8);  // self loop
        short8 o;
#pragma unroll
        for (int j = 0; j < 8; j++)
            o[j] = (short)f2bf((acc[j] + bf2f((unsigned short)sv[j])) * dv);
        *(short8*)(agg_p + a_addr(i, sub * 8)) = o;
    }
}

// ---------------- fused: z GEMM -> LDS; lin GEMM pre-barrier; gate GEMM; epilogue --------
// block = 16 rows x 256 cols, 4 waves; wave wv owns cols [wv*64, wv*64+64). 2 barriers.
// 16-row tile: acc regs 32/thread (round-8's 64), 2x blocks (3125) for latency hiding.
__global__ void k_fused(const unsigned short* __restrict__ agg_p,
                        const unsigned short* __restrict__ xs_p,
                        const unsigned short* __restrict__ Wp_gcn,
                        const unsigned short* __restrict__ Wp_lin,
                        const unsigned short* __restrict__ Wp_gate,
                        const float* __restrict__ b_gcn,
                        const float* __restrict__ bg,
                        const float* __restrict__ bl,
                        unsigned short* __restrict__ out_pre,  // [npad][256]
                        float* __restrict__ colsum,
                        float* __restrict__ colsumsq, int n) {
    __shared__ unsigned short z_lds[16 * ZSTR];   // 8.25 KB
    __shared__ unsigned short o_lds[16 * ZSTR];   // 8.25 KB

    int tid = threadIdx.x;
    int wv = tid >> 6;
    int lane = tid & 63;
    int l15 = lane & 15;
    int quad = lane >> 4;
    int row0 = blockIdx.x * 16;
    int rt0 = blockIdx.x;

    // ---- phase A: z = tanh(agg @ W_gcn + b_gcn), K=64 ----
    {
        f32x4 accz[4];
#pragma unroll
        for (int c = 0; c < 4; c++) accz[c] = (f32x4){0.f, 0.f, 0.f, 0.f};
#pragma unroll
        for (int kc = 0; kc < 2; kc++) {
            short8 af = *(const short8*)(agg_p + ((long)(rt0 * 2 + kc) << 9) + lane * 8);
            short8 bfr[4];
#pragma unroll
            for (int tn = 0; tn < 4; tn++)
                bfr[tn] = *(const short8*)(Wp_gcn + ((long)((wv * 4 + tn) * 2 + kc) << 9) + lane * 8);
#pragma unroll
            for (int tn = 0; tn < 4; tn++)
                accz[tn] = __builtin_amdgcn_mfma_f32_16x16x32_bf16(af, bfr[tn], accz[tn], 0, 0, 0);
        }
#pragma unroll
        for (int tn = 0; tn < 4; tn++) {
            int col = wv * 64 + tn * 16 + l15;
            float bias = b_gcn[col];
#pragma unroll
            for (int r2 = 0; r2 < 4; r2++) {
                int rl = quad * 4 + r2;
                z_lds[rl * ZSTR + col] = f2bf(fast_tanh(accz[tn][r2] + bias));
            }
        }
    }

    // ---- phase B1 (independent of z_lds — runs while LDS writes drain): xl = xs @ W_lin ----
    f32x4 acc2[4];
#pragma unroll
    for (int c = 0; c < 4; c++) acc2[c] = (f32x4){0.f, 0.f, 0.f, 0.f};
#pragma unroll
    for (int kc = 0; kc < 2; kc++) {
        short8 af = *(const short8*)(xs_p + ((long)(rt0 * 2 + kc) << 9) + lane * 8);
        short8 bfr[4];
#pragma unroll
        for (int tn = 0; tn < 4; tn++)
            bfr[tn] = *(const short8*)(Wp_lin + ((long)((wv * 4 + tn) * 2 + kc) << 9) + lane * 8);
#pragma unroll
        for (int tn = 0; tn < 4; tn++)
            acc2[tn] = __builtin_amdgcn_mfma_f32_16x16x32_bf16(af, bfr[tn], acc2[tn], 0, 0, 0);
    }
    __syncthreads();

    // ---- phase B2: logits = z @ W_gate, K=256, A from LDS, B lane-coalesced ----
    f32x4 acc1[4];
#pragma unroll
    for (int c = 0; c < 4; c++) acc1[c] = (f32x4){0.f, 0.f, 0.f, 0.f};
#pragma unroll
    for (int kc = 0; kc < 8; kc++) {
        short8 af = *(const short8*)(&z_lds[l15 * ZSTR + kc * 32 + quad * 8]);
        short8 bfr[4];
#pragma unroll
        for (int tn = 0; tn < 4; tn++)
            bfr[tn] = *(const short8*)(Wp_gate + ((long)((wv * 4 + tn) * 8 + kc) << 9) + lane * 8);
#pragma unroll
        for (int tn = 0; tn < 4; tn++)
            acc1[tn] = __builtin_amdgcn_mfma_f32_16x16x32_bf16(af, bfr[tn], acc1[tn], 0, 0, 0);
    }

    // ---- epilogue: o = relu((1-g)*xl + g*z) -> o_lds; BN partials ----
    float ls[4] = {0.f, 0.f, 0.f, 0.f};
    float lsq[4] = {0.f, 0.f, 0.f, 0.f};
#pragma unroll
    for (int tn = 0; tn < 4; tn++) {
        int col = wv * 64 + tn * 16 + l15;
        float bgc = bg[col];
        float blc = bl[col];
#pragma unroll
        for (int r2 = 0; r2 < 4; r2++) {
            int rl = quad * 4 + r2;
            int row = row0 + rl;
            if (row < n) {
                float g = fast_sigmoid(acc1[tn][r2] + bgc);
                float zv = bf2f(z_lds[rl * ZSTR + col]);
                float xv = acc2[tn][r2] + blc;
                float o = fmaxf((1.f - g) * xv + g * zv, 0.f);
                o_lds[rl * ZSTR + col] = f2bf(o);
                ls[tn] += o;
                lsq[tn] += o * o;
            }
        }
    }
    __syncthreads();

    // ---- coalesced tile store: 2 x dwordx4 per thread ----
#pragma unroll
    for (int it = 0; it < 2; it++) {
        int g = it * 2048 + tid * 8;       // shorts within 16x256 tile
        int row = g >> 8;
        int col = g & 255;
        short8 v = *(const short8*)(&o_lds[row * ZSTR + col]);
        *(short8*)(out_pre + (long)(row0 + row) * D_HID + col) = v;
    }

    // ---- BN partial atomics last (lets the tile store drain first) ----
#pragma unroll
    for (int tn = 0; tn < 4; tn++) {
        float s = ls[tn];
        float q = lsq[tn];
        s += __shfl_xor(s, 16);
        s += __shfl_xor(s, 32);
        q += __shfl_xor(q, 16);
        q += __shfl_xor(q, 32);
        if (quad == 0) {
            int col = wv * 64 + tn * 16 + l15;
            atomicAdd(&colsum[col], s);
            atomicAdd(&colsumsq[col], q);
        }
    }
}

// ---------------- BN apply (finalize folded in): bf16 in -> fp32 out, 8 elems/thread ----
__global__ void k_bn_apply(const unsigned short* __restrict__ op, float* __restrict__ out,
                           const float* __restrict__ colsum, const float* __restrict__ colsumsq,
                           const float* __restrict__ gamma, const float* __restrict__ beta,
                           int n, int total8) {
    int i8 = blockIdx.x * blockDim.x + threadIdx.x;
    if (i8 >= total8) return;
    long idx = (long)i8 * 8;
    short8 p = *(const short8*)(op + idx);
    int c = (int)(idx & (D_HID - 1));
    float inv_n = 1.0f / (float)n;
    float vo[8];
#pragma unroll
    for (int j = 0; j < 8; j++) {
        float mu = colsum[c + j] * inv_n;
        float var = colsumsq[c + j] * inv_n - mu * mu;
        float sc = gamma[c + j] * rsqrtf(var + BN_EPS);
        vo[j] = bf2f((unsigned short)p[j]) * sc + (beta[c + j] - mu * sc);
    }
    float4 v0 = {vo[0], vo[1], vo[2], vo[3]};
    float4 v1 = {vo[4], vo[5], vo[6], vo[7]};
    *(float4*)(out + idx) = v0;
    *(float4*)(out + idx + 4) = v1;
}

extern "C" void kernel_launch(void* const* d_in, const int* in_sizes, int n_in,
                              void* d_out, int out_size, void* d_ws, size_t ws_size,
                              hipStream_t stream) {
    const float* xs     = (const float*)d_in[0];
    const int*   eidx   = (const int*)d_in[1];
    const float* W_gcn  = (const float*)d_in[2];
    const float* b_gcn  = (const float*)d_in[3];
    const float* W_lin  = (const float*)d_in[4];
    const float* b_lin  = (const float*)d_in[5];
    const float* W_gate = (const float*)d_in[6];
    const float* b_gate = (const float*)d_in[7];
    const float* gamma  = (const float*)d_in[8];
    const float* beta   = (const float*)d_in[9];
    float* out = (float*)d_out;

    const int n = in_sizes[0] / D_IN;   // 50000
    const int E = in_sizes[1] / 2;      // 800000
    const int npad = (n + 63) & ~63;

    // workspace layout (512B aligned)
    char* ws = (char*)d_ws;
    size_t off = 0;
    auto alloc = [&](size_t bytes) {
        char* p = ws + off;
        off += (bytes + 511) & ~(size_t)511;
        return p;
    };
    int*            cnt      = (int*)alloc((size_t)n * 4);
    int*            part     = (int*)alloc((size_t)n * 4);
    int*            bsum     = (int*)alloc(1024);
    int*            offs     = (int*)alloc((size_t)n * 4);
    int*            cursor   = (int*)alloc((size_t)n * 4);
    int*            csr_src  = (int*)alloc((size_t)(E + 64) * 4);
    float*          dinv     = (float*)alloc((size_t)n * 4);
    unsigned short* xscaled  = (unsigned short*)alloc((size_t)(n + 1) * D_IN * 2);  // +1 zero row
    unsigned short* xs_p     = (unsigned short*)alloc((size_t)npad * D_IN * 2);
    unsigned short* agg_p    = (unsigned short*)alloc((size_t)npad * D_IN * 2);
    unsigned short* out_pre  = (unsigned short*)alloc((size_t)npad * D_HID * 2);
    unsigned short* Wp_gcn   = (unsigned short*)alloc((size_t)D_IN * D_HID * 2);
    unsigned short* Wp_lin   = (unsigned short*)alloc((size_t)D_IN * D_HID * 2);
    unsigned short* Wp_gate  = (unsigned short*)alloc((size_t)D_HID * D_HID * 2);
    float*          colsum   = (float*)alloc(D_HID * 4);
    float*          colsumsq = (float*)alloc(D_HID * 4);
    (void)ws_size;

    const int B = 256;
    const int nb = (n + 255) / 256;

    // 1. setup: zero counters/BN accums + pack weights
    k_setup<<<(98304 + B - 1) / B, B, 0, stream>>>(W_gcn, W_lin, W_gate, Wp_gcn, Wp_lin, Wp_gate,
                                                   cnt, colsum, colsumsq, n);
    // 2. count in-edges per node (4 edges/thread)
    k_count<<<(E / 4 + B - 1) / B, B, 0, stream>>>(eidx, cnt, E);
    // 3. exclusive scan; fixup fused with feature prep (+ zero sentinel row)
    k_scan1<<<nb, 256, 0, stream>>>(cnt, part, bsum, n);
    k_scan2<<<1, 256, 0, stream>>>(bsum, nb);
    k_scan3p<<<(n * 8 + 8 + B - 1) / B, B, 0, stream>>>(part, bsum, offs, cursor,
                                                        xs, cnt, dinv, xscaled, xs_p, n);
    // 4. scatter edges to CSR-by-dst (4 edges/thread)
    k_scatter<<<(E / 4 + B - 1) / B, B, 0, stream>>>(eidx, cursor, csr_src, E);
    // 5. gather aggregation (wave per node, uniform trip count, sentinel clamp)
    k_gather<<<(n + 3) / 4, B, 0, stream>>>(csr_src, offs, cnt, xscaled, dinv, agg_p, n);
    // 6. fused z-GEMM + gate-GEMM + lin-GEMM + epilogue + BN partials (16-row tiles)
    k_fused<<<(n + 15) / 16, B, 0, stream>>>(agg_p, xs_p, Wp_gcn, Wp_lin, Wp_gate,
                                             b_gcn, b_gate, b_lin, out_pre, colsum, colsumsq, n);
    // 7. BN apply (finalize folded in; bf16 -> fp32)
    {
        int total8 = n * D_HID / 8;
        k_bn_apply<<<(total8 + B - 1) / B, B, 0, stream>>>(out_pre, out, colsum, colsumsq,
                                                           gamma, beta, n, total8);
    }
}

// Round 10
// 271.427 us; speedup vs baseline: 1.1541x; 1.1541x over previous
//
#include <hip/hip_runtime.h>
#include <math.h>

#define NN 50000
#define NE 800000
#define D_IN 64
#define D_HID 256
#define BN_EPS 1e-5f
#define ZSTR 264   // LDS tile row stride in shorts (+8 pad: 16B-aligned rows, spread banks)

typedef __attribute__((ext_vector_type(8))) short short8;
typedef __attribute__((ext_vector_type(4))) float f32x4;

static __device__ __forceinline__ unsigned short f2bf(float f) {
    unsigned int u = __builtin_bit_cast(unsigned int, f);
    u += 0x7FFFu + ((u >> 16) & 1u);   // round-to-nearest-even
    return (unsigned short)(u >> 16);
}
static __device__ __forceinline__ float bf2f(unsigned short s) {
    unsigned int u = ((unsigned int)s) << 16;
    return __builtin_bit_cast(float, u);
}
// fast sigmoid: rcp(1+e^-x). Saturates cleanly at +/-inf, no NaN.
static __device__ __forceinline__ float fast_sigmoid(float x) {
    return __builtin_amdgcn_rcpf(1.0f + __expf(-x));
}
// fast tanh: 1 - 2*rcp(e^{2x}+1). Saturates cleanly, no NaN.
static __device__ __forceinline__ float fast_tanh(float x) {
    return 1.0f - 2.0f * __builtin_amdgcn_rcpf(__expf(2.0f * x) + 1.0f);
}

// A-frag-linear address for element (row i, feature k):
// ((i>>4)*2 + (k>>5))*512 + (((k>>3)&3)*16 + (i&15))*8 + (k&7)
static __device__ __forceinline__ long a_addr(int i, int k) {
    return ((long)((i >> 4) * 2 + (k >> 5)) << 9) + ((((k >> 3) & 3) * 16 + (i & 15)) << 3) + (k & 7);
}

// ---------------- pre: pack all weights (B-frag-linear bf16) + count in-edges -----------
// Wp[((ct*KC + kc)*64 + lane)*8 + j] = W[(kc*32 + (lane>>4)*8 + j)*256 + ct*16 + (lane&15)]
__global__ void k_pre(const float* __restrict__ W_gcn, const float* __restrict__ W_lin,
                      const float* __restrict__ W_gate,
                      unsigned short* __restrict__ Wp_gcn, unsigned short* __restrict__ Wp_lin,
                      unsigned short* __restrict__ Wp_gate,
                      const int* __restrict__ eidx, int* __restrict__ cnt, int E) {
    int idx = blockIdx.x * blockDim.x + threadIdx.x;
    if (idx < 98304) {
        const float* W;
        unsigned short* Wp;
        int KC, o;
        if (idx < 16384)      { W = W_gcn;  Wp = Wp_gcn;  KC = 2; o = idx; }
        else if (idx < 32768) { W = W_lin;  Wp = Wp_lin;  KC = 2; o = idx - 16384; }
        else                  { W = W_gate; Wp = Wp_gate; KC = 8; o = idx - 32768; }
        int j = o & 7;
        int lane = (o >> 3) & 63;
        int rest = o >> 9;
        int kc = rest % KC;
        int ct = rest / KC;
        int col = ct * 16 + (lane & 15);
        int k = kc * 32 + (lane >> 4) * 8 + j;
        Wp[o] = f2bf(W[k * D_HID + col]);
    }
    if (idx * 4 < E) {
        int4 d = *(const int4*)(eidx + E + idx * 4);
        atomicAdd(&cnt[d.x], 1);
        atomicAdd(&cnt[d.y], 1);
        atomicAdd(&cnt[d.z], 1);
        atomicAdd(&cnt[d.w], 1);
    }
}

// ---------------- scan (atomic-ticket) + prep fused ----------------
// blocks < nb: block-local exclusive scan of cnt, block base via atomicAdd(gtotal).
// CSR ranges only need to be disjoint — global order is irrelevant.
// all blocks: bf16 feature prep (xscaled row-major, xs_p frag-linear) + dinv + sentinel.
__global__ void k_scanprep(const float* __restrict__ xs, const int* __restrict__ cnt,
                           int* __restrict__ offs, int* __restrict__ cursor,
                           float* __restrict__ dinv, unsigned short* __restrict__ xscaled,
                           unsigned short* __restrict__ xs_p, int* __restrict__ gtotal, int n) {
    int t = threadIdx.x;
    int b = blockIdx.x;
    int nb = (n + 255) >> 8;
    if (b < nb) {
        __shared__ int s[256];
        __shared__ int sbase;
        int i = b * 256 + t;
        int v = (i < n) ? cnt[i] : 0;
        s[t] = v;
        __syncthreads();
        for (int d = 1; d < 256; d <<= 1) {
            int t2 = (t >= d) ? s[t - d] : 0;
            __syncthreads();
            s[t] += t2;
            __syncthreads();
        }
        int incl = s[t];
        if (t == 255) sbase = atomicAdd(gtotal, incl);  // incl@255 = block total
        __syncthreads();
        if (i < n) {
            int o = sbase + incl - v;
            offs[i] = o;
            cursor[i] = o;
        }
    }
    int idx = b * 256 + t;
    if (idx >= n * 8) {
        if (idx < n * 8 + 8) {  // zero sentinel row n (gather tail clamp target)
            short8 zv = (short8){0, 0, 0, 0, 0, 0, 0, 0};
            *(short8*)(xscaled + (long)n * D_IN + (idx - n * 8) * 8) = zv;
        }
        return;
    }
    int i = idx >> 3;
    int sub = idx & 7;
    float dv = rsqrtf(1.0f + (float)cnt[i]);
    if (sub == 0) dinv[i] = dv;
    const float* p = xs + (long)i * D_IN + sub * 8;
    float4 f0 = *(const float4*)p;
    float4 f1 = *(const float4*)(p + 4);
    float vals[8] = {f0.x, f0.y, f0.z, f0.w, f1.x, f1.y, f1.z, f1.w};
    short8 xsc, xsb;
#pragma unroll
    for (int j = 0; j < 8; j++) {
        xsc[j] = (short)f2bf(vals[j] * dv);
        xsb[j] = (short)f2bf(vals[j]);
    }
    *(short8*)(xscaled + (long)i * D_IN + sub * 8) = xsc;
    *(short8*)(xs_p + a_addr(i, sub * 8)) = xsb;
}

// ---------------- scatter edges into CSR-by-dst order: 4 edges/thread ----------------
__global__ void k_scatter(const int* __restrict__ eidx, int* __restrict__ cursor,
                          int* __restrict__ csr_src, int E) {
    int e4 = blockIdx.x * blockDim.x + threadIdx.x;
    if (e4 * 4 >= E) return;
    int4 s = *(const int4*)(eidx + e4 * 4);
    int4 d = *(const int4*)(eidx + E + e4 * 4);
    csr_src[atomicAdd(&cursor[d.x], 1)] = s.x;
    csr_src[atomicAdd(&cursor[d.y], 1)] = s.y;
    csr_src[atomicAdd(&cursor[d.z], 1)] = s.z;
    csr_src[atomicAdd(&cursor[d.w], 1)] = s.w;
}

// ---------------- gather aggregation: wave per node, 8 rows x 16B/lane per round ---------
__global__ __launch_bounds__(256) void k_gather(const int* __restrict__ csr_src,
                                                const int* __restrict__ offs,
                                                const int* __restrict__ cnt,
                                                const unsigned short* __restrict__ xscaled,
                                                const float* __restrict__ dinv,
                                                unsigned short* __restrict__ agg_p, int n) {
    int wv = threadIdx.x >> 6;
    int lane = threadIdx.x & 63;
    int sub = lane & 7;
    int grp = lane >> 3;
    int i = blockIdx.x * 4 + wv;
    if (i >= n) return;
    int start = offs[i];
    int c = cnt[i];
    float acc[8];
#pragma unroll
    for (int j = 0; j < 8; j++) acc[j] = 0.f;
    for (int base = 0; base < c; base += 64) {
        int m = c - base;
        m = m < 64 ? m : 64;
        int idxv = (lane < m) ? csr_src[start + base + lane] : 0;
        int tmax = (m + 7) >> 3;          // wave-uniform trip count
        for (int t = 0; t < tmax; t++) {
            int e = t * 8 + grp;
            int rowv = __shfl(idxv, e);
            int row = (e < m) ? rowv : n;  // clamp tail to zero sentinel row
            short8 v = *(const short8*)(xscaled + (long)row * D_IN + sub * 8);
#pragma unroll
            for (int j = 0; j < 8; j++) acc[j] += bf2f((unsigned short)v[j]);
        }
    }
#pragma unroll
    for (int d = 8; d <= 32; d <<= 1)
#pragma unroll
        for (int j = 0; j < 8; j++) acc[j] += __shfl_xor(acc[j], d);
    if (grp == 0) {
        float dv = dinv[i];
        short8 sv = *(const short8*)(xscaled + (long)i * D_IN + sub * 8);  // self loop
        short8 o;
#pragma unroll
        for (int j = 0; j < 8; j++)
            o[j] = (short)f2bf((acc[j] + bf2f((unsigned short)sv[j])) * dv);
        *(short8*)(agg_p + a_addr(i, sub * 8)) = o;
    }
}

// ---------------- fused v3: 64 rows/block, weights loaded ONCE per block ----------------
// 4 row-tiles of 16; loop-inverted so B-frags amortize over 4 tiles (round-9 lesson:
// loads-per-MFMA, not occupancy, is the binding constraint). xl packed bf16 in VGPRs;
// z/o share one LDS tile in-place. 3 barriers.
__global__ void k_fused(const unsigned short* __restrict__ agg_p,
                        const unsigned short* __restrict__ xs_p,
                        const unsigned short* __restrict__ Wp_gcn,
                        const unsigned short* __restrict__ Wp_lin,
                        const unsigned short* __restrict__ Wp_gate,
                        const float* __restrict__ b_gcn,
                        const float* __restrict__ bg,
                        const float* __restrict__ bl,
                        unsigned short* __restrict__ out_pre,  // [npad][256]
                        float* __restrict__ colsum,
                        float* __restrict__ colsumsq, int n) {
    __shared__ unsigned short z_lds[64 * ZSTR];   // 33.8 KB (z, then o in-place)

    int tid = threadIdx.x;
    int wv = tid >> 6;
    int lane = tid & 63;
    int l15 = lane & 15;
    int quad = lane >> 4;
    int row0 = blockIdx.x * 64;
    int rt0 = blockIdx.x * 4;

    // ---- phase A: z = tanh(agg @ W_gcn + b), K=64; gcn B-frags hoisted across 4 tiles ----
    {
        short8 wg[2][4];
#pragma unroll
        for (int kc = 0; kc < 2; kc++)
#pragma unroll
            for (int tn = 0; tn < 4; tn++)
                wg[kc][tn] = *(const short8*)(Wp_gcn + ((long)((wv * 4 + tn) * 2 + kc) << 9) + lane * 8);
        float bias[4];
#pragma unroll
        for (int tn = 0; tn < 4; tn++) bias[tn] = b_gcn[wv * 64 + tn * 16 + l15];
#pragma unroll
        for (int r = 0; r < 4; r++) {
            f32x4 accz[4];
#pragma unroll
            for (int c = 0; c < 4; c++) accz[c] = (f32x4){0.f, 0.f, 0.f, 0.f};
#pragma unroll
            for (int kc = 0; kc < 2; kc++) {
                short8 af = *(const short8*)(agg_p + ((long)((rt0 + r) * 2 + kc) << 9) + lane * 8);
#pragma unroll
                for (int tn = 0; tn < 4; tn++)
                    accz[tn] = __builtin_amdgcn_mfma_f32_16x16x32_bf16(af, wg[kc][tn], accz[tn], 0, 0, 0);
            }
#pragma unroll
            for (int tn = 0; tn < 4; tn++) {
                int col = wv * 64 + tn * 16 + l15;
#pragma unroll
                for (int r2 = 0; r2 < 4; r2++)
                    z_lds[(r * 16 + quad * 4 + r2) * ZSTR + col] = f2bf(fast_tanh(accz[tn][r2] + bias[tn]));
            }
        }
    }

    // ---- phase B1: xl = xs @ W_lin, K=64; result packed bf16 into 32 VGPRs ----
    uint2 xlp[4][4];
    {
        short8 wl[2][4];
#pragma unroll
        for (int kc = 0; kc < 2; kc++)
#pragma unroll
            for (int tn = 0; tn < 4; tn++)
                wl[kc][tn] = *(const short8*)(Wp_lin + ((long)((wv * 4 + tn) * 2 + kc) << 9) + lane * 8);
#pragma unroll
        for (int r = 0; r < 4; r++) {
            f32x4 accl[4];
#pragma unroll
            for (int c = 0; c < 4; c++) accl[c] = (f32x4){0.f, 0.f, 0.f, 0.f};
#pragma unroll
            for (int kc = 0; kc < 2; kc++) {
                short8 af = *(const short8*)(xs_p + ((long)((rt0 + r) * 2 + kc) << 9) + lane * 8);
#pragma unroll
                for (int tn = 0; tn < 4; tn++)
                    accl[tn] = __builtin_amdgcn_mfma_f32_16x16x32_bf16(af, wl[kc][tn], accl[tn], 0, 0, 0);
            }
#pragma unroll
            for (int tn = 0; tn < 4; tn++) {
                xlp[r][tn].x = (unsigned int)f2bf(accl[tn][0]) | ((unsigned int)f2bf(accl[tn][1]) << 16);
                xlp[r][tn].y = (unsigned int)f2bf(accl[tn][2]) | ((unsigned int)f2bf(accl[tn][3]) << 16);
            }
        }
    }
    __syncthreads();

    // ---- phase B2: logits = z @ W_gate, K=256; gate B-frags amortized over 4 tiles ----
    f32x4 acc1[4][4];
#pragma unroll
    for (int r = 0; r < 4; r++)
#pragma unroll
        for (int c = 0; c < 4; c++) acc1[r][c] = (f32x4){0.f, 0.f, 0.f, 0.f};
#pragma unroll
    for (int kc = 0; kc < 8; kc++) {
        short8 bfr[4];
#pragma unroll
        for (int tn = 0; tn < 4; tn++)
            bfr[tn] = *(const short8*)(Wp_gate + ((long)((wv * 4 + tn) * 8 + kc) << 9) + lane * 8);
#pragma unroll
        for (int r = 0; r < 4; r++) {
            short8 af = *(const short8*)(&z_lds[(r * 16 + l15) * ZSTR + kc * 32 + quad * 8]);
#pragma unroll
            for (int tn = 0; tn < 4; tn++)
                acc1[r][tn] = __builtin_amdgcn_mfma_f32_16x16x32_bf16(af, bfr[tn], acc1[r][tn], 0, 0, 0);
        }
    }
    __syncthreads();   // all B2 LDS reads done before in-place o overwrite

    // ---- epilogue: o = relu((1-g)*xl + g*z) -> z_lds in place; BN partials ----
    float ls[4] = {0.f, 0.f, 0.f, 0.f};
    float lsq[4] = {0.f, 0.f, 0.f, 0.f};
#pragma unroll
    for (int tn = 0; tn < 4; tn++) {
        int col = wv * 64 + tn * 16 + l15;
        float bgc = bg[col];
        float blc = bl[col];
#pragma unroll
        for (int r = 0; r < 4; r++) {
            uint2 pk = xlp[r][tn];
#pragma unroll
            for (int r2 = 0; r2 < 4; r2++) {
                int rl = r * 16 + quad * 4 + r2;
                int row = row0 + rl;
                if (row < n) {
                    float g = fast_sigmoid(acc1[r][tn][r2] + bgc);
                    float zv = bf2f(z_lds[rl * ZSTR + col]);
                    unsigned int w = (r2 & 2) ? pk.y : pk.x;
                    float xv = bf2f((unsigned short)(w >> ((r2 & 1) * 16))) + blc;
                    float o = fmaxf((1.f - g) * xv + g * zv, 0.f);
                    z_lds[rl * ZSTR + col] = f2bf(o);
                    ls[tn] += o;
                    lsq[tn] += o * o;
                }
            }
        }
    }
    __syncthreads();

    // ---- coalesced tile store: 8 x dwordx4 per thread ----
#pragma unroll
    for (int it = 0; it < 8; it++) {
        int g = it * 2048 + tid * 8;       // shorts within 64x256 tile
        int row = g >> 8;
        int col = g & 255;
        short8 v = *(const short8*)(&z_lds[row * ZSTR + col]);
        *(short8*)(out_pre + (long)(row0 + row) * D_HID + col) = v;
    }

    // ---- BN partial atomics last ----
#pragma unroll
    for (int tn = 0; tn < 4; tn++) {
        float s = ls[tn];
        float q = lsq[tn];
        s += __shfl_xor(s, 16);
        s += __shfl_xor(s, 32);
        q += __shfl_xor(q, 16);
        q += __shfl_xor(q, 32);
        if (quad == 0) {
            int col = wv * 64 + tn * 16 + l15;
            atomicAdd(&colsum[col], s);
            atomicAdd(&colsumsq[col], q);
        }
    }
}

// ---------------- BN apply (finalize folded in): bf16 in -> fp32 out, 8 elems/thread ----
__global__ void k_bn_apply(const unsigned short* __restrict__ op, float* __restrict__ out,
                           const float* __restrict__ colsum, const float* __restrict__ colsumsq,
                           const float* __restrict__ gamma, const float* __restrict__ beta,
                           int n, int total8) {
    int i8 = blockIdx.x * blockDim.x + threadIdx.x;
    if (i8 >= total8) return;
    long idx = (long)i8 * 8;
    short8 p = *(const short8*)(op + idx);
    int c = (int)(idx & (D_HID - 1));
    float inv_n = 1.0f / (float)n;
    float vo[8];
#pragma unroll
    for (int j = 0; j < 8; j++) {
        float mu = colsum[c + j] * inv_n;
        float var = colsumsq[c + j] * inv_n - mu * mu;
        float sc = gamma[c + j] * rsqrtf(var + BN_EPS);
        vo[j] = bf2f((unsigned short)p[j]) * sc + (beta[c + j] - mu * sc);
    }
    float4 v0 = {vo[0], vo[1], vo[2], vo[3]};
    float4 v1 = {vo[4], vo[5], vo[6], vo[7]};
    *(float4*)(out + idx) = v0;
    *(float4*)(out + idx + 4) = v1;
}

extern "C" void kernel_launch(void* const* d_in, const int* in_sizes, int n_in,
                              void* d_out, int out_size, void* d_ws, size_t ws_size,
                              hipStream_t stream) {
    const float* xs     = (const float*)d_in[0];
    const int*   eidx   = (const int*)d_in[1];
    const float* W_gcn  = (const float*)d_in[2];
    const float* b_gcn  = (const float*)d_in[3];
    const float* W_lin  = (const float*)d_in[4];
    const float* b_lin  = (const float*)d_in[5];
    const float* W_gate = (const float*)d_in[6];
    const float* b_gate = (const float*)d_in[7];
    const float* gamma  = (const float*)d_in[8];
    const float* beta   = (const float*)d_in[9];
    float* out = (float*)d_out;

    const int n = in_sizes[0] / D_IN;   // 50000
    const int E = in_sizes[1] / 2;      // 800000
    const int npad = (n + 63) & ~63;

    // workspace layout (512B aligned). First span [cnt..gtotal] is zeroed by one memset.
    char* ws = (char*)d_ws;
    size_t off = 0;
    auto alloc = [&](size_t bytes) {
        char* p = ws + off;
        off += (bytes + 511) & ~(size_t)511;
        return p;
    };
    size_t zero_begin = off;
    int*            cnt      = (int*)alloc((size_t)n * 4);
    float*          colsum   = (float*)alloc(D_HID * 4);
    float*          colsumsq = (float*)alloc(D_HID * 4);
    int*            gtotal   = (int*)alloc(4);
    size_t zero_end = off;
    int*            offs     = (int*)alloc((size_t)n * 4);
    int*            cursor   = (int*)alloc((size_t)n * 4);
    int*            csr_src  = (int*)alloc((size_t)(E + 64) * 4);
    float*          dinv     = (float*)alloc((size_t)n * 4);
    unsigned short* xscaled  = (unsigned short*)alloc((size_t)(n + 1) * D_IN * 2);  // +1 zero row
    unsigned short* xs_p     = (unsigned short*)alloc((size_t)npad * D_IN * 2);
    unsigned short* agg_p    = (unsigned short*)alloc((size_t)npad * D_IN * 2);
    unsigned short* out_pre  = (unsigned short*)alloc((size_t)npad * D_HID * 2);
    unsigned short* Wp_gcn   = (unsigned short*)alloc((size_t)D_IN * D_HID * 2);
    unsigned short* Wp_lin   = (unsigned short*)alloc((size_t)D_IN * D_HID * 2);
    unsigned short* Wp_gate  = (unsigned short*)alloc((size_t)D_HID * D_HID * 2);
    (void)ws_size;

    const int B = 256;

    // 0. zero counters + BN accumulators + scan ticket (single memset node)
    hipMemsetAsync(ws + zero_begin, 0, zero_end - zero_begin, stream);
    // 1. pack weights + count in-edges
    k_pre<<<(E / 4 + B - 1) / B, B, 0, stream>>>(W_gcn, W_lin, W_gate, Wp_gcn, Wp_lin, Wp_gate,
                                                 eidx, cnt, E);
    // 2. atomic-ticket scan (offs/cursor) + bf16 feature prep + sentinel
    k_scanprep<<<(n * 8 + 8 + B - 1) / B, B, 0, stream>>>(xs, cnt, offs, cursor, dinv,
                                                          xscaled, xs_p, gtotal, n);
    // 3. scatter edges to CSR-by-dst
    k_scatter<<<(E / 4 + B - 1) / B, B, 0, stream>>>(eidx, cursor, csr_src, E);
    // 4. gather aggregation (wave per node)
    k_gather<<<(n + 3) / 4, B, 0, stream>>>(csr_src, offs, cnt, xscaled, dinv, agg_p, n);
    // 5. fused GEMMs + epilogue + BN partials (64-row blocks, weights loaded once/block)
    k_fused<<<npad / 64, B, 0, stream>>>(agg_p, xs_p, Wp_gcn, Wp_lin, Wp_gate,
                                         b_gcn, b_gate, b_lin, out_pre, colsum, colsumsq, n);
    // 6. BN apply (finalize folded in; bf16 -> fp32)
    {
        int total8 = n * D_HID / 8;
        k_bn_apply<<<(total8 + B - 1) / B, B, 0, stream>>>(out_pre, out, colsum, colsumsq,
                                                           gamma, beta, n, total8);
    }
}

// Round 11
// 265.811 us; speedup vs baseline: 1.1785x; 1.0211x over previous
//
#include <hip/hip_runtime.h>
#include <math.h>

#define NN 50000
#define NE 800000
#define D_IN 64
#define D_HID 256
#define BN_EPS 1e-5f
#define ZSTR 264   // LDS tile row stride in shorts (+8 pad: 16B-aligned rows, spread banks)

typedef __attribute__((ext_vector_type(8))) short short8;
typedef __attribute__((ext_vector_type(4))) float f32x4;

static __device__ __forceinline__ unsigned short f2bf(float f) {
    unsigned int u = __builtin_bit_cast(unsigned int, f);
    u += 0x7FFFu + ((u >> 16) & 1u);   // round-to-nearest-even
    return (unsigned short)(u >> 16);
}
static __device__ __forceinline__ float bf2f(unsigned short s) {
    unsigned int u = ((unsigned int)s) << 16;
    return __builtin_bit_cast(float, u);
}
// fast sigmoid: rcp(1+e^-x). Saturates cleanly at +/-inf, no NaN.
static __device__ __forceinline__ float fast_sigmoid(float x) {
    return __builtin_amdgcn_rcpf(1.0f + __expf(-x));
}
// fast tanh: 1 - 2*rcp(e^{2x}+1). Saturates cleanly, no NaN.
static __device__ __forceinline__ float fast_tanh(float x) {
    return 1.0f - 2.0f * __builtin_amdgcn_rcpf(__expf(2.0f * x) + 1.0f);
}

// A-frag-linear address for element (row i, feature k):
// ((i>>4)*2 + (k>>5))*512 + (((k>>3)&3)*16 + (i&15))*8 + (k&7)
static __device__ __forceinline__ long a_addr(int i, int k) {
    return ((long)((i >> 4) * 2 + (k >> 5)) << 9) + ((((k >> 3) & 3) * 16 + (i & 15)) << 3) + (k & 7);
}

// ---------------- pre: pack all weights (B-frag-linear bf16) + count in-edges -----------
__global__ __launch_bounds__(256) void k_pre(const float* __restrict__ W_gcn,
                      const float* __restrict__ W_lin, const float* __restrict__ W_gate,
                      unsigned short* __restrict__ Wp_gcn, unsigned short* __restrict__ Wp_lin,
                      unsigned short* __restrict__ Wp_gate,
                      const int* __restrict__ eidx, int* __restrict__ cnt, int E) {
    int idx = blockIdx.x * blockDim.x + threadIdx.x;
    if (idx < 98304) {
        const float* W;
        unsigned short* Wp;
        int KC, o;
        if (idx < 16384)      { W = W_gcn;  Wp = Wp_gcn;  KC = 2; o = idx; }
        else if (idx < 32768) { W = W_lin;  Wp = Wp_lin;  KC = 2; o = idx - 16384; }
        else                  { W = W_gate; Wp = Wp_gate; KC = 8; o = idx - 32768; }
        int j = o & 7;
        int lane = (o >> 3) & 63;
        int rest = o >> 9;
        int kc = rest % KC;
        int ct = rest / KC;
        int col = ct * 16 + (lane & 15);
        int k = kc * 32 + (lane >> 4) * 8 + j;
        Wp[o] = f2bf(W[k * D_HID + col]);
    }
    if (idx * 4 < E) {
        int4 d = *(const int4*)(eidx + E + idx * 4);
        atomicAdd(&cnt[d.x], 1);
        atomicAdd(&cnt[d.y], 1);
        atomicAdd(&cnt[d.z], 1);
        atomicAdd(&cnt[d.w], 1);
    }
}

// ---------------- scan (atomic-ticket) + prep fused ----------------
__global__ __launch_bounds__(256) void k_scanprep(const float* __restrict__ xs,
                           const int* __restrict__ cnt,
                           int* __restrict__ offs, int* __restrict__ cursor,
                           float* __restrict__ dinv, unsigned short* __restrict__ xscaled,
                           unsigned short* __restrict__ xs_p, int* __restrict__ gtotal, int n) {
    int t = threadIdx.x;
    int b = blockIdx.x;
    int nb = (n + 255) >> 8;
    if (b < nb) {
        __shared__ int s[256];
        __shared__ int sbase;
        int i = b * 256 + t;
        int v = (i < n) ? cnt[i] : 0;
        s[t] = v;
        __syncthreads();
        for (int d = 1; d < 256; d <<= 1) {
            int t2 = (t >= d) ? s[t - d] : 0;
            __syncthreads();
            s[t] += t2;
            __syncthreads();
        }
        int incl = s[t];
        if (t == 255) sbase = atomicAdd(gtotal, incl);  // incl@255 = block total
        __syncthreads();
        if (i < n) {
            int o = sbase + incl - v;
            offs[i] = o;
            cursor[i] = o;
        }
    }
    int idx = b * 256 + t;
    if (idx >= n * 8) {
        if (idx < n * 8 + 8) {  // zero sentinel row n (gather tail clamp target)
            short8 zv = (short8){0, 0, 0, 0, 0, 0, 0, 0};
            *(short8*)(xscaled + (long)n * D_IN + (idx - n * 8) * 8) = zv;
        }
        return;
    }
    int i = idx >> 3;
    int sub = idx & 7;
    float dv = rsqrtf(1.0f + (float)cnt[i]);
    if (sub == 0) dinv[i] = dv;
    const float* p = xs + (long)i * D_IN + sub * 8;
    float4 f0 = *(const float4*)p;
    float4 f1 = *(const float4*)(p + 4);
    float vals[8] = {f0.x, f0.y, f0.z, f0.w, f1.x, f1.y, f1.z, f1.w};
    short8 xsc, xsb;
#pragma unroll
    for (int j = 0; j < 8; j++) {
        xsc[j] = (short)f2bf(vals[j] * dv);
        xsb[j] = (short)f2bf(vals[j]);
    }
    *(short8*)(xscaled + (long)i * D_IN + sub * 8) = xsc;
    *(short8*)(xs_p + a_addr(i, sub * 8)) = xsb;
}

// ---------------- scatter edges into CSR-by-dst (ushort entries): 4 edges/thread --------
// ushort csr: 1.6MB footprint keeps lines L2-resident so scattered stores merge
// (round-10: 4B entries -> 52.8MB WRITE_SIZE, one dirty 64B line per edge).
__global__ __launch_bounds__(256) void k_scatter(const int* __restrict__ eidx,
                          int* __restrict__ cursor,
                          unsigned short* __restrict__ csr_src, int E) {
    int e4 = blockIdx.x * blockDim.x + threadIdx.x;
    if (e4 * 4 >= E) return;
    int4 s = *(const int4*)(eidx + e4 * 4);
    int4 d = *(const int4*)(eidx + E + e4 * 4);
    csr_src[atomicAdd(&cursor[d.x], 1)] = (unsigned short)s.x;
    csr_src[atomicAdd(&cursor[d.y], 1)] = (unsigned short)s.y;
    csr_src[atomicAdd(&cursor[d.z], 1)] = (unsigned short)s.z;
    csr_src[atomicAdd(&cursor[d.w], 1)] = (unsigned short)s.w;
}

// ---------------- gather aggregation: wave per node, 8 rows x 16B/lane per round ---------
__global__ __launch_bounds__(256) void k_gather(const unsigned short* __restrict__ csr_src,
                                                const int* __restrict__ offs,
                                                const int* __restrict__ cnt,
                                                const unsigned short* __restrict__ xscaled,
                                                const float* __restrict__ dinv,
                                                unsigned short* __restrict__ agg_p, int n) {
    int wv = threadIdx.x >> 6;
    int lane = threadIdx.x & 63;
    int sub = lane & 7;
    int grp = lane >> 3;
    int i = blockIdx.x * 4 + wv;
    if (i >= n) return;
    int start = offs[i];
    int c = cnt[i];
    float acc[8];
#pragma unroll
    for (int j = 0; j < 8; j++) acc[j] = 0.f;
    for (int base = 0; base < c; base += 64) {
        int m = c - base;
        m = m < 64 ? m : 64;
        int idxv = (lane < m) ? (int)csr_src[start + base + lane] : 0;
        int tmax = (m + 7) >> 3;          // wave-uniform trip count
        for (int t = 0; t < tmax; t++) {
            int e = t * 8 + grp;
            int rowv = __shfl(idxv, e);
            int row = (e < m) ? rowv : n;  // clamp tail to zero sentinel row
            short8 v = *(const short8*)(xscaled + (long)row * D_IN + sub * 8);
#pragma unroll
            for (int j = 0; j < 8; j++) acc[j] += bf2f((unsigned short)v[j]);
        }
    }
#pragma unroll
    for (int d = 8; d <= 32; d <<= 1)
#pragma unroll
        for (int j = 0; j < 8; j++) acc[j] += __shfl_xor(acc[j], d);
    if (grp == 0) {
        float dv = dinv[i];
        short8 sv = *(const short8*)(xscaled + (long)i * D_IN + sub * 8);  // self loop
        short8 o;
#pragma unroll
        for (int j = 0; j < 8; j++)
            o[j] = (short)f2bf((acc[j] + bf2f((unsigned short)sv[j])) * dv);
        *(short8*)(agg_p + a_addr(i, sub * 8)) = o;
    }
}

// ---------------- fused v4: 64 rows/block, per-row-tile pipeline, no spills -------------
// launch_bounds(256) is mandatory: without it the allocator caps at 64 VGPR and spills
// (round-10: 83MB scratch traffic). Per row-tile r: B1(16 regs) -> B2(acc1[4], 16 regs)
// -> epilogue packs o into o_pk (32 regs total) — replaces round-10's 96-reg live set.
__global__ __launch_bounds__(256) void k_fused(const unsigned short* __restrict__ agg_p,
                        const unsigned short* __restrict__ xs_p,
                        const unsigned short* __restrict__ Wp_gcn,
                        const unsigned short* __restrict__ Wp_lin,
                        const unsigned short* __restrict__ Wp_gate,
                        const float* __restrict__ b_gcn,
                        const float* __restrict__ bg,
                        const float* __restrict__ bl,
                        unsigned short* __restrict__ out_pre,  // [npad][256]
                        float* __restrict__ colsum,
                        float* __restrict__ colsumsq, int n) {
    __shared__ unsigned short z_lds[64 * ZSTR];   // 33.8 KB (z, then o in-place)

    int tid = threadIdx.x;
    int wv = tid >> 6;
    int lane = tid & 63;
    int l15 = lane & 15;
    int quad = lane >> 4;
    int row0 = blockIdx.x * 64;
    int rt0 = blockIdx.x * 4;

    // ---- phase A: z = tanh(agg @ W_gcn + b), K=64; gcn B-frags hoisted across 4 tiles ----
    {
        short8 wg[2][4];
#pragma unroll
        for (int kc = 0; kc < 2; kc++)
#pragma unroll
            for (int tn = 0; tn < 4; tn++)
                wg[kc][tn] = *(const short8*)(Wp_gcn + ((long)((wv * 4 + tn) * 2 + kc) << 9) + lane * 8);
        float bias[4];
#pragma unroll
        for (int tn = 0; tn < 4; tn++) bias[tn] = b_gcn[wv * 64 + tn * 16 + l15];
#pragma unroll
        for (int r = 0; r < 4; r++) {
            f32x4 accz[4];
#pragma unroll
            for (int c = 0; c < 4; c++) accz[c] = (f32x4){0.f, 0.f, 0.f, 0.f};
#pragma unroll
            for (int kc = 0; kc < 2; kc++) {
                short8 af = *(const short8*)(agg_p + ((long)((rt0 + r) * 2 + kc) << 9) + lane * 8);
#pragma unroll
                for (int tn = 0; tn < 4; tn++)
                    accz[tn] = __builtin_amdgcn_mfma_f32_16x16x32_bf16(af, wg[kc][tn], accz[tn], 0, 0, 0);
            }
#pragma unroll
            for (int tn = 0; tn < 4; tn++) {
                int col = wv * 64 + tn * 16 + l15;
#pragma unroll
                for (int r2 = 0; r2 < 4; r2++)
                    z_lds[(r * 16 + quad * 4 + r2) * ZSTR + col] = f2bf(fast_tanh(accz[tn][r2] + bias[tn]));
            }
        }
    }
    __syncthreads();

    // ---- per row-tile: xl GEMM -> gate GEMM -> epilogue (o packed bf16 in regs) ----
    uint2 o_pk[4][4];
    float ls[4] = {0.f, 0.f, 0.f, 0.f};
    float lsq[4] = {0.f, 0.f, 0.f, 0.f};
    float bgc[4], blc[4];
#pragma unroll
    for (int tn = 0; tn < 4; tn++) {
        int col = wv * 64 + tn * 16 + l15;
        bgc[tn] = bg[col];
        blc[tn] = bl[col];
    }
#pragma unroll
    for (int r = 0; r < 4; r++) {
        // B1: xl = xs @ W_lin for this tile
        f32x4 accl[4];
#pragma unroll
        for (int c = 0; c < 4; c++) accl[c] = (f32x4){0.f, 0.f, 0.f, 0.f};
#pragma unroll
        for (int kc = 0; kc < 2; kc++) {
            short8 af = *(const short8*)(xs_p + ((long)((rt0 + r) * 2 + kc) << 9) + lane * 8);
#pragma unroll
            for (int tn = 0; tn < 4; tn++) {
                short8 wl = *(const short8*)(Wp_lin + ((long)((wv * 4 + tn) * 2 + kc) << 9) + lane * 8);
                accl[tn] = __builtin_amdgcn_mfma_f32_16x16x32_bf16(af, wl, accl[tn], 0, 0, 0);
            }
        }
        // B2: logits = z @ W_gate, K=256, A from LDS
        f32x4 acc1[4];
#pragma unroll
        for (int c = 0; c < 4; c++) acc1[c] = (f32x4){0.f, 0.f, 0.f, 0.f};
#pragma unroll
        for (int kc = 0; kc < 8; kc++) {
            short8 af = *(const short8*)(&z_lds[(r * 16 + l15) * ZSTR + kc * 32 + quad * 8]);
#pragma unroll
            for (int tn = 0; tn < 4; tn++) {
                short8 bfr = *(const short8*)(Wp_gate + ((long)((wv * 4 + tn) * 8 + kc) << 9) + lane * 8);
                acc1[tn] = __builtin_amdgcn_mfma_f32_16x16x32_bf16(af, bfr, acc1[tn], 0, 0, 0);
            }
        }
        // epilogue: o = relu((1-g)*xl + g*z), packed bf16 into o_pk (z_lds write deferred)
#pragma unroll
        for (int tn = 0; tn < 4; tn++) {
            int col = wv * 64 + tn * 16 + l15;
            unsigned short op[4];
#pragma unroll
            for (int r2 = 0; r2 < 4; r2++) {
                int rl = r * 16 + quad * 4 + r2;
                int row = row0 + rl;
                float g = fast_sigmoid(acc1[tn][r2] + bgc[tn]);
                float zv = bf2f(z_lds[rl * ZSTR + col]);
                float xv = accl[tn][r2] + blc[tn];
                float o = fmaxf((1.f - g) * xv + g * zv, 0.f);
                op[r2] = f2bf(o);
                if (row < n) {
                    ls[tn] += o;
                    lsq[tn] += o * o;
                }
            }
            o_pk[r][tn].x = (unsigned int)op[0] | ((unsigned int)op[1] << 16);
            o_pk[r][tn].y = (unsigned int)op[2] | ((unsigned int)op[3] << 16);
        }
    }
    __syncthreads();   // all z_lds reads (B2 + epilogue) complete before o write-back

    // ---- write o back into z_lds (in place) ----
#pragma unroll
    for (int r = 0; r < 4; r++)
#pragma unroll
        for (int tn = 0; tn < 4; tn++) {
            int col = wv * 64 + tn * 16 + l15;
            int rl = r * 16 + quad * 4;
            *(unsigned int*)(&z_lds[(rl + 0) * ZSTR + col]) ; // no-op guard (kept simple below)
            z_lds[(rl + 0) * ZSTR + col] = (unsigned short)(o_pk[r][tn].x & 0xFFFF);
            z_lds[(rl + 1) * ZSTR + col] = (unsigned short)(o_pk[r][tn].x >> 16);
            z_lds[(rl + 2) * ZSTR + col] = (unsigned short)(o_pk[r][tn].y & 0xFFFF);
            z_lds[(rl + 3) * ZSTR + col] = (unsigned short)(o_pk[r][tn].y >> 16);
        }
    __syncthreads();

    // ---- coalesced tile store: 8 x dwordx4 per thread ----
#pragma unroll
    for (int it = 0; it < 8; it++) {
        int g = it * 2048 + tid * 8;       // shorts within 64x256 tile
        int row = g >> 8;
        int col = g & 255;
        short8 v = *(const short8*)(&z_lds[row * ZSTR + col]);
        *(short8*)(out_pre + (long)(row0 + row) * D_HID + col) = v;
    }

    // ---- BN partial atomics last ----
#pragma unroll
    for (int tn = 0; tn < 4; tn++) {
        float s = ls[tn];
        float q = lsq[tn];
        s += __shfl_xor(s, 16);
        s += __shfl_xor(s, 32);
        q += __shfl_xor(q, 16);
        q += __shfl_xor(q, 32);
        if (quad == 0) {
            int col = wv * 64 + tn * 16 + l15;
            atomicAdd(&colsum[col], s);
            atomicAdd(&colsumsq[col], q);
        }
    }
}

// ---------------- BN apply (finalize folded in): bf16 in -> fp32 out, 8 elems/thread ----
__global__ __launch_bounds__(256) void k_bn_apply(const unsigned short* __restrict__ op,
                           float* __restrict__ out,
                           const float* __restrict__ colsum, const float* __restrict__ colsumsq,
                           const float* __restrict__ gamma, const float* __restrict__ beta,
                           int n, int total8) {
    int i8 = blockIdx.x * blockDim.x + threadIdx.x;
    if (i8 >= total8) return;
    long idx = (long)i8 * 8;
    short8 p = *(const short8*)(op + idx);
    int c = (int)(idx & (D_HID - 1));
    float inv_n = 1.0f / (float)n;
    float vo[8];
#pragma unroll
    for (int j = 0; j < 8; j++) {
        float mu = colsum[c + j] * inv_n;
        float var = colsumsq[c + j] * inv_n - mu * mu;
        float sc = gamma[c + j] * rsqrtf(var + BN_EPS);
        vo[j] = bf2f((unsigned short)p[j]) * sc + (beta[c + j] - mu * sc);
    }
    float4 v0 = {vo[0], vo[1], vo[2], vo[3]};
    float4 v1 = {vo[4], vo[5], vo[6], vo[7]};
    *(float4*)(out + idx) = v0;
    *(float4*)(out + idx + 4) = v1;
}

extern "C" void kernel_launch(void* const* d_in, const int* in_sizes, int n_in,
                              void* d_out, int out_size, void* d_ws, size_t ws_size,
                              hipStream_t stream) {
    const float* xs     = (const float*)d_in[0];
    const int*   eidx   = (const int*)d_in[1];
    const float* W_gcn  = (const float*)d_in[2];
    const float* b_gcn  = (const float*)d_in[3];
    const float* W_lin  = (const float*)d_in[4];
    const float* b_lin  = (const float*)d_in[5];
    const float* W_gate = (const float*)d_in[6];
    const float* b_gate = (const float*)d_in[7];
    const float* gamma  = (const float*)d_in[8];
    const float* beta   = (const float*)d_in[9];
    float* out = (float*)d_out;

    const int n = in_sizes[0] / D_IN;   // 50000
    const int E = in_sizes[1] / 2;      // 800000
    const int npad = (n + 63) & ~63;

    // workspace layout (512B aligned). First span [cnt..gtotal] is zeroed by one memset.
    char* ws = (char*)d_ws;
    size_t off = 0;
    auto alloc = [&](size_t bytes) {
        char* p = ws + off;
        off += (bytes + 511) & ~(size_t)511;
        return p;
    };
    size_t zero_begin = off;
    int*            cnt      = (int*)alloc((size_t)n * 4);
    float*          colsum   = (float*)alloc(D_HID * 4);
    float*          colsumsq = (float*)alloc(D_HID * 4);
    int*            gtotal   = (int*)alloc(4);
    size_t zero_end = off;
    int*            offs     = (int*)alloc((size_t)n * 4);
    int*            cursor   = (int*)alloc((size_t)n * 4);
    unsigned short* csr_src  = (unsigned short*)alloc((size_t)(E + 64) * 2);  // ushort entries
    float*          dinv     = (float*)alloc((size_t)n * 4);
    unsigned short* xscaled  = (unsigned short*)alloc((size_t)(n + 1) * D_IN * 2);  // +1 zero row
    unsigned short* xs_p     = (unsigned short*)alloc((size_t)npad * D_IN * 2);
    unsigned short* agg_p    = (unsigned short*)alloc((size_t)npad * D_IN * 2);
    unsigned short* out_pre  = (unsigned short*)alloc((size_t)npad * D_HID * 2);
    unsigned short* Wp_gcn   = (unsigned short*)alloc((size_t)D_IN * D_HID * 2);
    unsigned short* Wp_lin   = (unsigned short*)alloc((size_t)D_IN * D_HID * 2);
    unsigned short* Wp_gate  = (unsigned short*)alloc((size_t)D_HID * D_HID * 2);
    (void)ws_size;

    const int B = 256;

    // 0. zero counters + BN accumulators + scan ticket (single memset node)
    hipMemsetAsync(ws + zero_begin, 0, zero_end - zero_begin, stream);
    // 1. pack weights + count in-edges
    k_pre<<<(E / 4 + B - 1) / B, B, 0, stream>>>(W_gcn, W_lin, W_gate, Wp_gcn, Wp_lin, Wp_gate,
                                                 eidx, cnt, E);
    // 2. atomic-ticket scan (offs/cursor) + bf16 feature prep + sentinel
    k_scanprep<<<(n * 8 + 8 + B - 1) / B, B, 0, stream>>>(xs, cnt, offs, cursor, dinv,
                                                          xscaled, xs_p, gtotal, n);
    // 3. scatter edges to CSR-by-dst (ushort)
    k_scatter<<<(E / 4 + B - 1) / B, B, 0, stream>>>(eidx, cursor, csr_src, E);
    // 4. gather aggregation (wave per node)
    k_gather<<<(n + 3) / 4, B, 0, stream>>>(csr_src, offs, cnt, xscaled, dinv, agg_p, n);
    // 5. fused GEMMs + epilogue + BN partials (64-row blocks, spill-free)
    k_fused<<<npad / 64, B, 0, stream>>>(agg_p, xs_p, Wp_gcn, Wp_lin, Wp_gate,
                                         b_gcn, b_gate, b_lin, out_pre, colsum, colsumsq, n);
    // 6. BN apply (finalize folded in; bf16 -> fp32)
    {
        int total8 = n * D_HID / 8;
        k_bn_apply<<<(total8 + B - 1) / B, B, 0, stream>>>(out_pre, out, colsum, colsumsq,
                                                           gamma, beta, n, total8);
    }
}